// Round 9
// baseline (209.896 us; speedup 1.0000x reference)
//
#include <hip/hip_runtime.h>

// Attention_11940009083141 — MI355X, round 9.
// B=2, S=2048, HID=1024, NH=16, HD=64. FP32 in/out; bf16 MFMA internally.
//
// r8 post-mortem: flash VALU-bound (~1050 VALU cyc/wave-tile vs 160 MFMA:
// exp mul+trans, 3-op manual f2bf, acc-zero movs); qkv 3 blocks/CU
// latency-bound (~300 TF).
//
// Round-9:
//  * flash: exp2 path (log2e folded into q scale), native __bf16 cast
//    (v_cvt_pk_bf16_f32), zero-acc MFMA trick, pl swizzled at stride 64
//    -> LDS 40960 B = exactly 4 blocks/CU, launch_bounds(256,4).
//  * qkv -> 64x128 tiles (grid 1536 = 6/CU), same for out_gemm (256,4).
//
// ws (32MB): q[0,8M) k[8,16M) vT[16,24M) attn[24,32M); Wob over dead q.
// d_out scratch: pre-qkv Wqb@0 Wkb@2M Wvb@4M xb@6M; post-qkv O1@0, L0/L1@8M.

typedef unsigned short u16;
typedef __bf16 bf16x8 __attribute__((ext_vector_type(8)));
typedef float  f32x4  __attribute__((ext_vector_type(4)));
typedef u16    u16x8  __attribute__((ext_vector_type(8)));
typedef u16    u16x4  __attribute__((ext_vector_type(4)));

#define HID 1024
#define SEQ 2048
#define NH  16
#define HD  64

#if __has_builtin(__builtin_amdgcn_exp2f)
#define EXP2F(x) __builtin_amdgcn_exp2f(x)
#else
#define EXP2F(x) exp2f(x)
#endif

__device__ __forceinline__ float bf2f(u16 u) { return __uint_as_float(((unsigned)u) << 16); }
// f32 -> bf16 RNE via native cast (v_cvt_pk_bf16_f32 on gfx950)
__device__ __forceinline__ u16 f2bf(float f) {
  union { __bf16 h; u16 u; } c;
  c.h = (__bf16)f;
  return c.u;
}
__device__ __forceinline__ void gl_lds16(const void* g, void* l) {
  __builtin_amdgcn_global_load_lds((const __attribute__((address_space(1))) void*)g,
                                   (__attribute__((address_space(3))) void*)l, 16, 0, 0);
}
__device__ __forceinline__ void stage_f32(const float* __restrict__ src, u16* dst) {
  float4 f0 = *(const float4*)src;
  float4 f1 = *(const float4*)(src + 4);
  u16x8 o;
  o[0] = f2bf(f0.x); o[1] = f2bf(f0.y); o[2] = f2bf(f0.z); o[3] = f2bf(f0.w);
  o[4] = f2bf(f1.x); o[5] = f2bf(f1.y); o[6] = f2bf(f1.z); o[7] = f2bf(f1.w);
  *(u16x8*)dst = o;
}
// XOR chunk swizzle: logical 8-u16 chunk c of row r lives at physical chunk c^(r&7)
__device__ __forceinline__ int swz(int c, int r) { return c ^ (r & 7); }

// ---------------- fp32 -> bf16 converts ------------------------------------------------
__global__ void cvt_pre(const float* __restrict__ x,  const float* __restrict__ Wq,
                        const float* __restrict__ Wk, const float* __restrict__ Wv,
                        u16* __restrict__ xb, u16* __restrict__ Wqb,
                        u16* __restrict__ Wkb, u16* __restrict__ Wvb) {
  const int z = blockIdx.y;
  const float* src; u16* dst; int nchunk;
  switch (z) {
    case 0:  src = x;  dst = xb;  nchunk = 524288; break;
    case 1:  src = Wq; dst = Wqb; nchunk = 131072; break;
    case 2:  src = Wk; dst = Wkb; nchunk = 131072; break;
    default: src = Wv; dst = Wvb; nchunk = 131072; break;
  }
  const int i = blockIdx.x * 256 + threadIdx.x;
  if (i >= nchunk) return;
  stage_f32(src + (size_t)i * 8, dst + (size_t)i * 8);
}
__global__ void cvt_wo(const float* __restrict__ Wo, u16* __restrict__ Wob) {
  const int i = blockIdx.x * 256 + threadIdx.x;   // 131072 chunks
  stage_f32(Wo + (size_t)i * 8, Wob + (size_t)i * 8);
}

// ---------------- NT GEMM mainloop: 64x128 tile, BK=64, K=1024, two-sided DMA ---------
__device__ __forceinline__ void gemm64_mainloop(const u16* __restrict__ Aptr,
                                                const u16* __restrict__ Bptr,
                                                u16* a_lds, u16* b_lds,
                                                int m0, int n0, f32x4 (&acc)[2][4]) {
  const int tid  = threadIdx.x;
  const int w    = tid >> 6;
  const int lane = tid & 63;
  const int quad = lane >> 4, l15 = lane & 15;
  const int wm = (w >> 1) * 32, wn = (w & 1) * 64;
  const int srow = lane >> 3, sc = lane & 7;        // DMA roles: 8 rows x 8 chunks

  for (int k0 = 0; k0 < HID; k0 += 64) {
#pragma unroll
    for (int i = 0; i < 2; ++i) {                   // A: 8 segs (64 rows)
      const int seg = w * 2 + i, r = seg * 8 + srow;
      gl_lds16(Aptr + (size_t)(m0 + r) * HID + k0 + swz(sc, srow) * 8, a_lds + seg * 512);
    }
#pragma unroll
    for (int i = 0; i < 4; ++i) {                   // B: 16 segs (128 rows)
      const int seg = w * 4 + i, r = seg * 8 + srow;
      gl_lds16(Bptr + (size_t)(n0 + r) * HID + k0 + swz(sc, srow) * 8, b_lds + seg * 512);
    }
    __syncthreads();
#pragma unroll
    for (int kf = 0; kf < 2; ++kf) {
      bf16x8 af[2], bfr[4];
#pragma unroll
      for (int mt = 0; mt < 2; ++mt)
        af[mt] = *(const bf16x8*)&a_lds[(wm + mt * 16 + l15) * 64 + swz(kf * 4 + quad, l15) * 8];
#pragma unroll
      for (int nt = 0; nt < 4; ++nt)
        bfr[nt] = *(const bf16x8*)&b_lds[(wn + nt * 16 + l15) * 64 + swz(kf * 4 + quad, l15) * 8];
#pragma unroll
      for (int mt = 0; mt < 2; ++mt)
#pragma unroll
        for (int nt = 0; nt < 4; ++nt)
          acc[mt][nt] = __builtin_amdgcn_mfma_f32_16x16x32_bf16(af[mt], bfr[nt], acc[mt][nt], 0, 0, 0);
    }
    __syncthreads();
  }
}

// ---------------- QKV projection: 64x128 tiles, fused RoPE; z=2 writes vT --------------
// q scale folds 1/sqrt(D) AND log2(e) so flash can use raw exp2.
#define QS_LOG2E 0.18033688011112042f   // 0.125 * log2(e)
__global__ __launch_bounds__(256, 4) void qkv_gemm(const u16* __restrict__ xb,
                                                   const u16* __restrict__ Wqb,
                                                   const u16* __restrict__ Wkb,
                                                   const u16* __restrict__ Wvb,
                                                   u16* __restrict__ q, u16* __restrict__ k,
                                                   u16* __restrict__ vT) {
  __shared__ __align__(16) u16 a_lds[64 * 64];
  __shared__ __align__(16) u16 b_lds[128 * 64];
  const int z = blockIdx.z;
  const u16* W = (z == 0) ? Wqb : (z == 1) ? Wkb : Wvb;

  f32x4 acc[2][4];
#pragma unroll
  for (int i = 0; i < 2; ++i)
#pragma unroll
    for (int j = 0; j < 4; ++j) acc[i][j] = (f32x4){0.f, 0.f, 0.f, 0.f};

  const int m0 = blockIdx.y * 64, n0 = blockIdx.x * 128;
  gemm64_mainloop(xb, W, a_lds, b_lds, m0, n0, acc);

  const int tid = threadIdx.x, w = tid >> 6, lane = tid & 63;
  const int quad = lane >> 4, l15 = lane & 15;
  const int wm = (w >> 1) * 32, wn = (w & 1) * 64;

  if (z != 2) {   // fused NeoX rope: pairs (d, d+32) = (nt, nt+2) in-thread
    float fr[2];
    fr[0] = __expf(-(float)(l15)      * 0.2878231366242557f);   // 10000^(-d/32)
    fr[1] = __expf(-(float)(16 + l15) * 0.2878231366242557f);
    const float qs = (z == 0) ? QS_LOG2E : 1.f;
#pragma unroll
    for (int mt = 0; mt < 2; ++mt)
#pragma unroll
      for (int r = 0; r < 4; ++r) {
        const int s = (m0 + wm + mt * 16 + quad * 4 + r) & 2047;
#pragma unroll
        for (int p = 0; p < 2; ++p) {
          float c, sn;
          __sincosf((float)s * fr[p], &sn, &c);
          const float t1 = acc[mt][p][r], t2 = acc[mt][p + 2][r];
          acc[mt][p][r]     = (t1 * c - t2 * sn) * qs;
          acc[mt][p + 2][r] = (t2 * c + t1 * sn) * qs;
        }
      }
    u16* dst = (z == 0) ? q : k;
#pragma unroll
    for (int mt = 0; mt < 2; ++mt)
#pragma unroll
      for (int nt = 0; nt < 4; ++nt) {
        const int col = n0 + wn + nt * 16 + l15;       // h*64 + d
        const int h = col >> 6, d = col & 63;
#pragma unroll
        for (int r = 0; r < 4; ++r) {
          const int row = m0 + wm + mt * 16 + quad * 4 + r;   // b*2048 + s
          const int bh  = (row >> 11) * NH + h;
          dst[((size_t)bh * SEQ + (row & 2047)) * HD + d] = f2bf(acc[mt][nt][r]);
        }
      }
  } else {        // V: write transposed vT[bh][d][s] (4 consecutive s -> b64)
#pragma unroll
    for (int mt = 0; mt < 2; ++mt) {
      const int rowbase = m0 + wm + mt * 16 + quad * 4;   // b*2048 + s0, s0%4==0
      const int b = rowbase >> 11, s0 = rowbase & 2047;
#pragma unroll
      for (int nt = 0; nt < 4; ++nt) {
        const int col = n0 + wn + nt * 16 + l15;
        const int h = col >> 6, d = col & 63;
        u16x4 o;
#pragma unroll
        for (int r = 0; r < 4; ++r) o[r] = f2bf(acc[mt][nt][r]);
        *(u16x4*)&vT[((size_t)(b * NH + h) * HD + d) * SEQ + s0] = o;
      }
    }
  }
}

// ---------------- Flash split-K2: BM=128, BN=64, 16 tiles/block, partial O+L -----------
__global__ __launch_bounds__(256, 4) void flash(const u16* __restrict__ q,
                                                const u16* __restrict__ k,
                                                const u16* __restrict__ vT,
                                                u16* __restrict__ o0, u16* __restrict__ o1,
                                                float* __restrict__ L0, float* __restrict__ L1) {
  __shared__ __align__(16) u16 ktl[2 * 4096];      // K tiles [key][d], swizzled chunks
  __shared__ __align__(16) u16 vtl[2 * 4096];      // V^T tiles [d][key], swizzled chunks
  __shared__ __align__(16) u16 pl[4 * 16 * 64];    // per-wave P staging, swizzled chunks

  const int tid = threadIdx.x, w = tid >> 6, lane = tid & 63;
  const int quad = lane >> 4, l15 = lane & 15;
  const int srow = lane >> 3, sc = lane & 7;
  const int bh = blockIdx.y;
  const int q0 = blockIdx.x * 128;
  const int z  = blockIdx.z;                       // key half
  u16*   odst = z ? o1 : o0;
  float* Ldst = z ? L1 : L0;

  // Q frags for this wave's 32 q-rows (2 halves); q pre-scaled by 0.125*log2e
  bf16x8 qa[2][2];
#pragma unroll
  for (int qh = 0; qh < 2; ++qh) {
    const u16* qrow = q + ((size_t)bh * SEQ + q0 + w * 32 + qh * 16 + l15) * HD + quad * 8;
    qa[qh][0] = *(const bf16x8*)qrow;
    qa[qh][1] = *(const bf16x8*)(qrow + 32);
  }

  const f32x4 zero4 = (f32x4){0.f, 0.f, 0.f, 0.f};
  f32x4 oacc[2][4];
#pragma unroll
  for (int qh = 0; qh < 2; ++qh)
#pragma unroll
    for (int i = 0; i < 4; ++i) oacc[qh][i] = zero4;
  float L[2] = {0.f, 0.f};   // per-lane row sum for q = qh*16 + l15

  const u16* kbase = k  + (size_t)bh * SEQ * HD + (size_t)z * 1024 * HD;
  const u16* vtb   = vT + (size_t)bh * HD * SEQ + (size_t)z * 1024;

  // prologue: DMA tile 0 into buffer 0 — 64 rows = 8 segs of 8 rows (2 per wave)
#pragma unroll
  for (int i = 0; i < 2; ++i) {
    const int seg = w * 2 + i, r = seg * 8 + srow, col = swz(sc, srow) * 8;
    gl_lds16(kbase + (size_t)r * HD + col,  &ktl[seg * 512]);
    gl_lds16(vtb   + (size_t)r * SEQ + col, &vtl[seg * 512]);
  }
  __syncthreads();

  for (int t = 0; t < 16; ++t) {
    const int t0 = t * 64, buf = t & 1;
    if (t < 15) {   // DMA next tile (64 rows) into the other buffer
#pragma unroll
      for (int i = 0; i < 2; ++i) {
        const int seg = w * 2 + i, r = seg * 8 + srow, col = swz(sc, srow) * 8;
        gl_lds16(kbase + (size_t)(t0 + 64 + r) * HD + col, &ktl[(buf ^ 1) * 4096 + seg * 512]);
        gl_lds16(vtb   + (size_t)r * SEQ + t0 + 64 + col,  &vtl[(buf ^ 1) * 4096 + seg * 512]);
      }
    }

    // hoisted frags (shared across both q-halves)
    bf16x8 kfr[2][4], bvf[2][4];
#pragma unroll
    for (int kf = 0; kf < 2; ++kf)
#pragma unroll
      for (int nt = 0; nt < 4; ++nt) {
        kfr[kf][nt] = *(const bf16x8*)&ktl[buf * 4096 + (nt * 16 + l15) * 64 + swz(kf * 4 + quad, l15) * 8];
        bvf[kf][nt] = *(const bf16x8*)&vtl[buf * 4096 + (nt * 16 + l15) * 64 + swz(kf * 4 + quad, l15) * 8];
      }

    u16* pw = &pl[w * 16 * 64];
#pragma unroll
    for (int qh = 0; qh < 2; ++qh) {
      // S^T = K Q^T: rows m=key (quad*4+r), cols n=q (l15); C=zero4 (no init movs)
      f32x4 sv[4];
#pragma unroll
      for (int nt = 0; nt < 4; ++nt) {
        sv[nt] = __builtin_amdgcn_mfma_f32_16x16x32_bf16(kfr[0][nt], qa[qh][0], zero4, 0, 0, 0);
        sv[nt] = __builtin_amdgcn_mfma_f32_16x16x32_bf16(kfr[1][nt], qa[qh][1], sv[nt], 0, 0, 0);
      }
      // P^T = exp2(S^T); b64 writes into swizzled chunk layout (write chunk
      // cw = 2nt + (quad>>1), in-chunk offset 4*(quad&1))
#pragma unroll
      for (int nt = 0; nt < 4; ++nt) {
        u16x4 pk;
#pragma unroll
        for (int r = 0; r < 4; ++r) {
          const float pv = EXP2F(sv[nt][r]);
          L[qh] += pv;
          pk[r] = f2bf(pv);
        }
        const int cw = 2 * nt + (quad >> 1);
        *(u16x4*)&pw[l15 * 64 + swz(cw, l15) * 8 + 4 * (quad & 1)] = pk;
      }
      // O += P V  (A = P rows from LDS swizzled chunks, B = V^T frags)
#pragma unroll
      for (int kf = 0; kf < 2; ++kf) {
        bf16x8 ap = *(const bf16x8*)&pw[l15 * 64 + swz(kf * 4 + quad, l15) * 8];
#pragma unroll
        for (int dt = 0; dt < 4; ++dt)
          oacc[qh][dt] = __builtin_amdgcn_mfma_f32_16x16x32_bf16(ap, bvf[kf][dt], oacc[qh][dt], 0, 0, 0);
      }
    }
    __syncthreads();   // drains next-tile DMA; releases buffers
  }

  // L reduce across the 4 quads; write raw partials (no normalization here)
#pragma unroll
  for (int qh = 0; qh < 2; ++qh) {
    L[qh] += __shfl_xor(L[qh], 16, 64);
    L[qh] += __shfl_xor(L[qh], 32, 64);
    if (quad == 0) Ldst[(size_t)bh * SEQ + q0 + w * 32 + qh * 16 + l15] = L[qh];
  }

  const int b = bh >> 4, h = bh & 15;
#pragma unroll
  for (int qh = 0; qh < 2; ++qh)
#pragma unroll
    for (int r = 0; r < 4; ++r) {
      const int row = b * SEQ + q0 + w * 32 + qh * 16 + quad * 4 + r;
#pragma unroll
      for (int dt = 0; dt < 4; ++dt)
        odst[(size_t)row * HID + h * HD + dt * 16 + l15] = f2bf(oacc[qh][dt][r]);
    }
}

// ---------------- Combine: attn = (O0 + O1) / (L0 + L1), in place over O0 --------------
__global__ void combine(const u16* __restrict__ o1, const float* __restrict__ L0,
                        const float* __restrict__ L1, u16* __restrict__ attn) {
  const size_t base = ((size_t)blockIdx.x * 256 + threadIdx.x) * 8;
  const int row = (int)(base >> 10);            // [0,4096): b*2048+s
  const int h   = ((int)base & 1023) >> 6;
  const int bh  = (row >> 11) * NH + h;
  const int s   = row & 2047;
  const float inv = 1.f / (L0[(size_t)bh * SEQ + s] + L1[(size_t)bh * SEQ + s]);
  u16x8 a = *(const u16x8*)&attn[base];         // O0 partial (in place)
  u16x8 b = *(const u16x8*)&o1[base];
  u16x8 o;
#pragma unroll
  for (int j = 0; j < 8; ++j) o[j] = f2bf((bf2f(a[j]) + bf2f(b[j])) * inv);
  *(u16x8*)&attn[base] = o;
}

// ---------------- Output projection: 64x128 tiles (512 blocks) -------------------------
__global__ __launch_bounds__(256, 4) void out_gemm(const u16* __restrict__ attn,
                                                   const u16* __restrict__ Wob,
                                                   float* __restrict__ out) {
  __shared__ __align__(16) u16 a_lds[64 * 64];
  __shared__ __align__(16) u16 b_lds[128 * 64];
  f32x4 acc[2][4];
#pragma unroll
  for (int i = 0; i < 2; ++i)
#pragma unroll
    for (int j = 0; j < 4; ++j) acc[i][j] = (f32x4){0.f, 0.f, 0.f, 0.f};

  const int m0 = blockIdx.y * 64, n0 = blockIdx.x * 128;
  gemm64_mainloop(attn, Wob, a_lds, b_lds, m0, n0, acc);

  const int tid = threadIdx.x, w = tid >> 6, lane = tid & 63;
  const int quad = lane >> 4, l15 = lane & 15;
  const int wm = (w >> 1) * 32, wn = (w & 1) * 64;
#pragma unroll
  for (int mt = 0; mt < 2; ++mt)
#pragma unroll
    for (int nt = 0; nt < 4; ++nt) {
      const int col = n0 + wn + nt * 16 + l15;
#pragma unroll
      for (int r = 0; r < 4; ++r) {
        const int row = m0 + wm + mt * 16 + quad * 4 + r;
        out[(size_t)row * HID + col] = acc[mt][nt][r];
      }
    }
}

// ---------------- launch ---------------------------------------------------------------
extern "C" void kernel_launch(void* const* d_in, const int* in_sizes, int n_in,
                              void* d_out, int out_size, void* d_ws, size_t ws_size,
                              hipStream_t stream) {
  const float* x  = (const float*)d_in[0];
  const float* Wq = (const float*)d_in[1];
  const float* Wk = (const float*)d_in[2];
  const float* Wv = (const float*)d_in[3];
  const float* Wo = (const float*)d_in[4];
  float* out = (float*)d_out;

  // d_out as scratch (all dead before out_gemm's writes):
  char* os = (char*)d_out;
  u16* Wqb = (u16*)(os);                     // 2MB   (dead after qkv)
  u16* Wkb = (u16*)(os + (2u << 20));        // 2MB
  u16* Wvb = (u16*)(os + (4u << 20));        // 2MB
  u16* xb  = (u16*)(os + (6u << 20));        // 8MB
  u16*   o1 = (u16*)(os);                    // 8MB partial O (z=1), post-qkv
  float* L0 = (float*)(os + (8u << 20));     // 256KB
  float* L1 = (float*)(os + (8u << 20) + (256u << 10));

  char* ws = (char*)d_ws;                    // 32MB
  u16* q    = (u16*)(ws);                    // 8MB; dead after flash
  u16* Wob  = (u16*)(ws);                    // 2MB over dead q
  u16* k    = (u16*)(ws + (8u << 20));       // 8MB
  u16* vT   = (u16*)(ws + (16u << 20));      // 8MB  [bh][d][s]
  u16* attn = (u16*)(ws + (24u << 20));      // 8MB; partial O (z=0), then combined

  cvt_pre<<<dim3(2048, 4), 256, 0, stream>>>(x, Wq, Wk, Wv, xb, Wqb, Wkb, Wvb);
  qkv_gemm<<<dim3(8, 64, 3), 256, 0, stream>>>(xb, Wqb, Wkb, Wvb, q, k, vT);
  flash<<<dim3(16, 32, 2), 256, 0, stream>>>(q, k, vT, attn, o1, L0, L1);
  cvt_wo<<<dim3(512), 256, 0, stream>>>(Wo, Wob);
  combine<<<dim3(2048), 256, 0, stream>>>(o1, L0, L1, attn);
  out_gemm<<<dim3(8, 64), 256, 0, stream>>>(attn, Wob, out);
}

// Round 10
// 179.200 us; speedup vs baseline: 1.1713x; 1.1713x over previous
//
#include <hip/hip_runtime.h>

// Attention_11940009083141 — MI355X, round 10.
// B=2, S=2048, HID=1024, NH=16, HD=64. FP32 in/out; bf16 MFMA internally.
//
// r9 post-mortem: flash VALU diet hit its counter (VALUBusy 44->28) but time
// was flat -> flash is barrier-latency bound, not VALU bound. qkv 64x128
// retile regressed (-15us: worse flops/staged-byte + occupancy tail).
//
// Round-10:
//  * flash BM=256: 4 q-halves per wave (64 q-rows), grid (8,32,2)=512 blocks.
//    2x MFMA per staged byte, K/V frags amortized over 4 qh, 4 independent
//    dependency chains between barriers. launch_bounds(256,2), LDS 40KB.
//  * qkv reverted to 128x128 tiles (r8 mainloop) with exp2 q-scale kept.
//
// ws (32MB): q[0,8M) k[8,16M) vT[16,24M) attn[24,32M); Wob over dead q.
// d_out scratch: pre-qkv Wqb@0 Wkb@2M Wvb@4M xb@6M; post-qkv O1@0, L0/L1@8M.

typedef unsigned short u16;
typedef __bf16 bf16x8 __attribute__((ext_vector_type(8)));
typedef float  f32x4  __attribute__((ext_vector_type(4)));
typedef u16    u16x8  __attribute__((ext_vector_type(8)));
typedef u16    u16x4  __attribute__((ext_vector_type(4)));

#define HID 1024
#define SEQ 2048
#define NH  16
#define HD  64

#if __has_builtin(__builtin_amdgcn_exp2f)
#define EXP2F(x) __builtin_amdgcn_exp2f(x)
#else
#define EXP2F(x) exp2f(x)
#endif

__device__ __forceinline__ float bf2f(u16 u) { return __uint_as_float(((unsigned)u) << 16); }
// f32 -> bf16 RNE via native cast
__device__ __forceinline__ u16 f2bf(float f) {
  union { __bf16 h; u16 u; } c;
  c.h = (__bf16)f;
  return c.u;
}
__device__ __forceinline__ void gl_lds16(const void* g, void* l) {
  __builtin_amdgcn_global_load_lds((const __attribute__((address_space(1))) void*)g,
                                   (__attribute__((address_space(3))) void*)l, 16, 0, 0);
}
__device__ __forceinline__ void stage_f32(const float* __restrict__ src, u16* dst) {
  float4 f0 = *(const float4*)src;
  float4 f1 = *(const float4*)(src + 4);
  u16x8 o;
  o[0] = f2bf(f0.x); o[1] = f2bf(f0.y); o[2] = f2bf(f0.z); o[3] = f2bf(f0.w);
  o[4] = f2bf(f1.x); o[5] = f2bf(f1.y); o[6] = f2bf(f1.z); o[7] = f2bf(f1.w);
  *(u16x8*)dst = o;
}
// XOR chunk swizzle: logical 8-u16 chunk c of row r lives at physical chunk c^(r&7)
__device__ __forceinline__ int swz(int c, int r) { return c ^ (r & 7); }

// ---------------- fp32 -> bf16 converts ------------------------------------------------
__global__ void cvt_pre(const float* __restrict__ x,  const float* __restrict__ Wq,
                        const float* __restrict__ Wk, const float* __restrict__ Wv,
                        u16* __restrict__ xb, u16* __restrict__ Wqb,
                        u16* __restrict__ Wkb, u16* __restrict__ Wvb) {
  const int z = blockIdx.y;
  const float* src; u16* dst; int nchunk;
  switch (z) {
    case 0:  src = x;  dst = xb;  nchunk = 524288; break;
    case 1:  src = Wq; dst = Wqb; nchunk = 131072; break;
    case 2:  src = Wk; dst = Wkb; nchunk = 131072; break;
    default: src = Wv; dst = Wvb; nchunk = 131072; break;
  }
  const int i = blockIdx.x * 256 + threadIdx.x;
  if (i >= nchunk) return;
  stage_f32(src + (size_t)i * 8, dst + (size_t)i * 8);
}
__global__ void cvt_wo(const float* __restrict__ Wo, u16* __restrict__ Wob) {
  const int i = blockIdx.x * 256 + threadIdx.x;   // 131072 chunks
  stage_f32(Wo + (size_t)i * 8, Wob + (size_t)i * 8);
}

// ---------------- NT GEMM mainloop: 128x128 tile, BK=64, K=1024, two-sided DMA --------
__device__ __forceinline__ void gemm_mainloop(const u16* __restrict__ Aptr,
                                              const u16* __restrict__ Bptr,
                                              u16* a_lds, u16* b_lds,
                                              int m0, int n0, f32x4 (&acc)[4][4]) {
  const int tid  = threadIdx.x;
  const int w    = tid >> 6;
  const int lane = tid & 63;
  const int quad = lane >> 4, l15 = lane & 15;
  const int wm = (w >> 1) * 64, wn = (w & 1) * 64;
  const int srow = lane >> 3, sc = lane & 7;        // DMA roles: 8 rows x 8 chunks

  for (int k0 = 0; k0 < HID; k0 += 64) {
#pragma unroll
    for (int i = 0; i < 4; ++i) {
      const int seg = w * 4 + i;                    // 16 segs of 8 rows per 128x64 tile
      const int r   = seg * 8 + srow;
      const int col = k0 + swz(sc, srow) * 8;       // swizzled source column
      gl_lds16(Aptr + (size_t)(m0 + r) * HID + col, a_lds + seg * 512);
      gl_lds16(Bptr + (size_t)(n0 + r) * HID + col, b_lds + seg * 512);
    }
    __syncthreads();
#pragma unroll
    for (int kf = 0; kf < 2; ++kf) {
      bf16x8 af[4], bfr[4];
#pragma unroll
      for (int mt = 0; mt < 4; ++mt)
        af[mt] = *(const bf16x8*)&a_lds[(wm + mt * 16 + l15) * 64 + swz(kf * 4 + quad, l15) * 8];
#pragma unroll
      for (int nt = 0; nt < 4; ++nt)
        bfr[nt] = *(const bf16x8*)&b_lds[(wn + nt * 16 + l15) * 64 + swz(kf * 4 + quad, l15) * 8];
#pragma unroll
      for (int mt = 0; mt < 4; ++mt)
#pragma unroll
        for (int nt = 0; nt < 4; ++nt)
          acc[mt][nt] = __builtin_amdgcn_mfma_f32_16x16x32_bf16(af[mt], bfr[nt], acc[mt][nt], 0, 0, 0);
    }
    __syncthreads();
  }
}

// ---------------- NT GEMM mainloop: 64x128 tile (out_gemm) -----------------------------
__device__ __forceinline__ void gemm64_mainloop(const u16* __restrict__ Aptr,
                                                const u16* __restrict__ Bptr,
                                                u16* a_lds, u16* b_lds,
                                                int m0, int n0, f32x4 (&acc)[2][4]) {
  const int tid  = threadIdx.x;
  const int w    = tid >> 6;
  const int lane = tid & 63;
  const int quad = lane >> 4, l15 = lane & 15;
  const int wm = (w >> 1) * 32, wn = (w & 1) * 64;
  const int srow = lane >> 3, sc = lane & 7;

  for (int k0 = 0; k0 < HID; k0 += 64) {
#pragma unroll
    for (int i = 0; i < 2; ++i) {                   // A: 8 segs (64 rows)
      const int seg = w * 2 + i, r = seg * 8 + srow;
      gl_lds16(Aptr + (size_t)(m0 + r) * HID + k0 + swz(sc, srow) * 8, a_lds + seg * 512);
    }
#pragma unroll
    for (int i = 0; i < 4; ++i) {                   // B: 16 segs (128 rows)
      const int seg = w * 4 + i, r = seg * 8 + srow;
      gl_lds16(Bptr + (size_t)(n0 + r) * HID + k0 + swz(sc, srow) * 8, b_lds + seg * 512);
    }
    __syncthreads();
#pragma unroll
    for (int kf = 0; kf < 2; ++kf) {
      bf16x8 af[2], bfr[4];
#pragma unroll
      for (int mt = 0; mt < 2; ++mt)
        af[mt] = *(const bf16x8*)&a_lds[(wm + mt * 16 + l15) * 64 + swz(kf * 4 + quad, l15) * 8];
#pragma unroll
      for (int nt = 0; nt < 4; ++nt)
        bfr[nt] = *(const bf16x8*)&b_lds[(wn + nt * 16 + l15) * 64 + swz(kf * 4 + quad, l15) * 8];
#pragma unroll
      for (int mt = 0; mt < 2; ++mt)
#pragma unroll
        for (int nt = 0; nt < 4; ++nt)
          acc[mt][nt] = __builtin_amdgcn_mfma_f32_16x16x32_bf16(af[mt], bfr[nt], acc[mt][nt], 0, 0, 0);
    }
    __syncthreads();
  }
}

// ---------------- QKV projection: 128x128 tiles, fused RoPE; z=2 writes vT -------------
// q scale folds 1/sqrt(D) AND log2(e) so flash can use raw exp2.
#define QS_LOG2E 0.18033688011112042f   // 0.125 * log2(e)
__global__ __launch_bounds__(256, 2) void qkv_gemm(const u16* __restrict__ xb,
                                                   const u16* __restrict__ Wqb,
                                                   const u16* __restrict__ Wkb,
                                                   const u16* __restrict__ Wvb,
                                                   u16* __restrict__ q, u16* __restrict__ k,
                                                   u16* __restrict__ vT) {
  __shared__ __align__(16) u16 a_lds[128 * 64];
  __shared__ __align__(16) u16 b_lds[128 * 64];
  const int z = blockIdx.z;
  const u16* W = (z == 0) ? Wqb : (z == 1) ? Wkb : Wvb;

  f32x4 acc[4][4];
#pragma unroll
  for (int i = 0; i < 4; ++i)
#pragma unroll
    for (int j = 0; j < 4; ++j) acc[i][j] = (f32x4){0.f, 0.f, 0.f, 0.f};

  const int m0 = blockIdx.y * 128, n0 = blockIdx.x * 128;
  gemm_mainloop(xb, W, a_lds, b_lds, m0, n0, acc);

  const int tid = threadIdx.x, w = tid >> 6, lane = tid & 63;
  const int quad = lane >> 4, l15 = lane & 15;
  const int wm = (w >> 1) * 64, wn = (w & 1) * 64;

  if (z != 2) {   // fused NeoX rope: pairs (d, d+32) = (nt, nt+2) in-thread
    float fr[2];
    fr[0] = __expf(-(float)(l15)      * 0.2878231366242557f);   // 10000^(-d/32)
    fr[1] = __expf(-(float)(16 + l15) * 0.2878231366242557f);
    const float qs = (z == 0) ? QS_LOG2E : 1.f;
#pragma unroll
    for (int mt = 0; mt < 4; ++mt)
#pragma unroll
      for (int r = 0; r < 4; ++r) {
        const int s = (m0 + wm + mt * 16 + quad * 4 + r) & 2047;
#pragma unroll
        for (int p = 0; p < 2; ++p) {
          float c, sn;
          __sincosf((float)s * fr[p], &sn, &c);
          const float t1 = acc[mt][p][r], t2 = acc[mt][p + 2][r];
          acc[mt][p][r]     = (t1 * c - t2 * sn) * qs;
          acc[mt][p + 2][r] = (t2 * c + t1 * sn) * qs;
        }
      }
    u16* dst = (z == 0) ? q : k;
#pragma unroll
    for (int mt = 0; mt < 4; ++mt)
#pragma unroll
      for (int nt = 0; nt < 4; ++nt) {
        const int col = n0 + wn + nt * 16 + l15;       // h*64 + d
        const int h = col >> 6, d = col & 63;
#pragma unroll
        for (int r = 0; r < 4; ++r) {
          const int row = m0 + wm + mt * 16 + quad * 4 + r;   // b*2048 + s
          const int bh  = (row >> 11) * NH + h;
          dst[((size_t)bh * SEQ + (row & 2047)) * HD + d] = f2bf(acc[mt][nt][r]);
        }
      }
  } else {        // V: write transposed vT[bh][d][s] (4 consecutive s -> b64)
#pragma unroll
    for (int mt = 0; mt < 4; ++mt) {
      const int rowbase = m0 + wm + mt * 16 + quad * 4;   // b*2048 + s0, s0%4==0
      const int b = rowbase >> 11, s0 = rowbase & 2047;
#pragma unroll
      for (int nt = 0; nt < 4; ++nt) {
        const int col = n0 + wn + nt * 16 + l15;
        const int h = col >> 6, d = col & 63;
        u16x4 o;
#pragma unroll
        for (int r = 0; r < 4; ++r) o[r] = f2bf(acc[mt][nt][r]);
        *(u16x4*)&vT[((size_t)(b * NH + h) * HD + d) * SEQ + s0] = o;
      }
    }
  }
}

// ---------------- Flash split-K2: BM=256 (4 waves x 64 q-rows), BN=64 ------------------
__global__ __launch_bounds__(256, 2) void flash(const u16* __restrict__ q,
                                                const u16* __restrict__ k,
                                                const u16* __restrict__ vT,
                                                u16* __restrict__ o0, u16* __restrict__ o1,
                                                float* __restrict__ L0, float* __restrict__ L1) {
  __shared__ __align__(16) u16 ktl[2 * 4096];      // K tiles [key][d], swizzled chunks
  __shared__ __align__(16) u16 vtl[2 * 4096];      // V^T tiles [d][key], swizzled chunks
  __shared__ __align__(16) u16 pl[4 * 16 * 64];    // per-wave P staging, swizzled chunks

  const int tid = threadIdx.x, w = tid >> 6, lane = tid & 63;
  const int quad = lane >> 4, l15 = lane & 15;
  const int srow = lane >> 3, sc = lane & 7;
  const int bh = blockIdx.y;
  const int q0 = blockIdx.x * 256;
  const int z  = blockIdx.z;                       // key half
  u16*   odst = z ? o1 : o0;
  float* Ldst = z ? L1 : L0;

  // Q frags for this wave's 64 q-rows (4 halves); q pre-scaled by 0.125*log2e
  bf16x8 qa[4][2];
#pragma unroll
  for (int qh = 0; qh < 4; ++qh) {
    const u16* qrow = q + ((size_t)bh * SEQ + q0 + w * 64 + qh * 16 + l15) * HD + quad * 8;
    qa[qh][0] = *(const bf16x8*)qrow;
    qa[qh][1] = *(const bf16x8*)(qrow + 32);
  }

  const f32x4 zero4 = (f32x4){0.f, 0.f, 0.f, 0.f};
  f32x4 oacc[4][4];
#pragma unroll
  for (int qh = 0; qh < 4; ++qh)
#pragma unroll
    for (int i = 0; i < 4; ++i) oacc[qh][i] = zero4;
  float L[4] = {0.f, 0.f, 0.f, 0.f};   // per-lane row sum for q = qh*16 + l15

  const u16* kbase = k  + (size_t)bh * SEQ * HD + (size_t)z * 1024 * HD;
  const u16* vtb   = vT + (size_t)bh * HD * SEQ + (size_t)z * 1024;

  // prologue: DMA tile 0 into buffer 0 — 64 rows = 8 segs of 8 rows (2 per wave)
#pragma unroll
  for (int i = 0; i < 2; ++i) {
    const int seg = w * 2 + i, r = seg * 8 + srow, col = swz(sc, srow) * 8;
    gl_lds16(kbase + (size_t)r * HD + col,  &ktl[seg * 512]);
    gl_lds16(vtb   + (size_t)r * SEQ + col, &vtl[seg * 512]);
  }
  __syncthreads();

  for (int t = 0; t < 16; ++t) {
    const int t0 = t * 64, buf = t & 1;
    if (t < 15) {   // DMA next tile (64 rows) into the other buffer
#pragma unroll
      for (int i = 0; i < 2; ++i) {
        const int seg = w * 2 + i, r = seg * 8 + srow, col = swz(sc, srow) * 8;
        gl_lds16(kbase + (size_t)(t0 + 64 + r) * HD + col, &ktl[(buf ^ 1) * 4096 + seg * 512]);
        gl_lds16(vtb   + (size_t)r * SEQ + t0 + 64 + col,  &vtl[(buf ^ 1) * 4096 + seg * 512]);
      }
    }

    // hoisted frags (shared across all four q-halves)
    bf16x8 kfr[2][4], bvf[2][4];
#pragma unroll
    for (int kf = 0; kf < 2; ++kf)
#pragma unroll
      for (int nt = 0; nt < 4; ++nt) {
        kfr[kf][nt] = *(const bf16x8*)&ktl[buf * 4096 + (nt * 16 + l15) * 64 + swz(kf * 4 + quad, l15) * 8];
        bvf[kf][nt] = *(const bf16x8*)&vtl[buf * 4096 + (nt * 16 + l15) * 64 + swz(kf * 4 + quad, l15) * 8];
      }

    u16* pw = &pl[w * 16 * 64];
#pragma unroll
    for (int qh = 0; qh < 4; ++qh) {
      // S^T = K Q^T: rows m=key (quad*4+r), cols n=q (l15); C=zero4 (no init movs)
      f32x4 sv[4];
#pragma unroll
      for (int nt = 0; nt < 4; ++nt) {
        sv[nt] = __builtin_amdgcn_mfma_f32_16x16x32_bf16(kfr[0][nt], qa[qh][0], zero4, 0, 0, 0);
        sv[nt] = __builtin_amdgcn_mfma_f32_16x16x32_bf16(kfr[1][nt], qa[qh][1], sv[nt], 0, 0, 0);
      }
      // P^T = exp2(S^T); b64 writes into swizzled chunk layout
#pragma unroll
      for (int nt = 0; nt < 4; ++nt) {
        u16x4 pk;
#pragma unroll
        for (int r = 0; r < 4; ++r) {
          const float pv = EXP2F(sv[nt][r]);
          L[qh] += pv;
          pk[r] = f2bf(pv);
        }
        const int cw = 2 * nt + (quad >> 1);
        *(u16x4*)&pw[l15 * 64 + swz(cw, l15) * 8 + 4 * (quad & 1)] = pk;
      }
      // O += P V  (A = P rows from LDS swizzled chunks, B = V^T frags); same-wave
      // DS ops are in-order, so reusing pw across qh is safe.
#pragma unroll
      for (int kf = 0; kf < 2; ++kf) {
        bf16x8 ap = *(const bf16x8*)&pw[l15 * 64 + swz(kf * 4 + quad, l15) * 8];
#pragma unroll
        for (int dt = 0; dt < 4; ++dt)
          oacc[qh][dt] = __builtin_amdgcn_mfma_f32_16x16x32_bf16(ap, bvf[kf][dt], oacc[qh][dt], 0, 0, 0);
      }
    }
    __syncthreads();   // drains next-tile DMA; releases buffers
  }

  // L reduce across the 4 quads; write raw partials (no normalization here)
#pragma unroll
  for (int qh = 0; qh < 4; ++qh) {
    L[qh] += __shfl_xor(L[qh], 16, 64);
    L[qh] += __shfl_xor(L[qh], 32, 64);
    if (quad == 0) Ldst[(size_t)bh * SEQ + q0 + w * 64 + qh * 16 + l15] = L[qh];
  }

  const int b = bh >> 4, h = bh & 15;
#pragma unroll
  for (int qh = 0; qh < 4; ++qh)
#pragma unroll
    for (int r = 0; r < 4; ++r) {
      const int row = b * SEQ + q0 + w * 64 + qh * 16 + quad * 4 + r;
#pragma unroll
      for (int dt = 0; dt < 4; ++dt)
        odst[(size_t)row * HID + h * HD + dt * 16 + l15] = f2bf(oacc[qh][dt][r]);
    }
}

// ---------------- Combine: attn = (O0 + O1) / (L0 + L1), in place over O0 --------------
__global__ void combine(const u16* __restrict__ o1, const float* __restrict__ L0,
                        const float* __restrict__ L1, u16* __restrict__ attn) {
  const size_t base = ((size_t)blockIdx.x * 256 + threadIdx.x) * 8;
  const int row = (int)(base >> 10);            // [0,4096): b*2048+s
  const int h   = ((int)base & 1023) >> 6;
  const int bh  = (row >> 11) * NH + h;
  const int s   = row & 2047;
  const float inv = 1.f / (L0[(size_t)bh * SEQ + s] + L1[(size_t)bh * SEQ + s]);
  u16x8 a = *(const u16x8*)&attn[base];         // O0 partial (in place)
  u16x8 b = *(const u16x8*)&o1[base];
  u16x8 o;
#pragma unroll
  for (int j = 0; j < 8; ++j) o[j] = f2bf((bf2f(a[j]) + bf2f(b[j])) * inv);
  *(u16x8*)&attn[base] = o;
}

// ---------------- Output projection: 64x128 tiles (512 blocks) -------------------------
__global__ __launch_bounds__(256, 4) void out_gemm(const u16* __restrict__ attn,
                                                   const u16* __restrict__ Wob,
                                                   float* __restrict__ out) {
  __shared__ __align__(16) u16 a_lds[64 * 64];
  __shared__ __align__(16) u16 b_lds[128 * 64];
  f32x4 acc[2][4];
#pragma unroll
  for (int i = 0; i < 2; ++i)
#pragma unroll
    for (int j = 0; j < 4; ++j) acc[i][j] = (f32x4){0.f, 0.f, 0.f, 0.f};

  const int m0 = blockIdx.y * 64, n0 = blockIdx.x * 128;
  gemm64_mainloop(attn, Wob, a_lds, b_lds, m0, n0, acc);

  const int tid = threadIdx.x, w = tid >> 6, lane = tid & 63;
  const int quad = lane >> 4, l15 = lane & 15;
  const int wm = (w >> 1) * 32, wn = (w & 1) * 64;
#pragma unroll
  for (int mt = 0; mt < 2; ++mt)
#pragma unroll
    for (int nt = 0; nt < 4; ++nt) {
      const int col = n0 + wn + nt * 16 + l15;
#pragma unroll
      for (int r = 0; r < 4; ++r) {
        const int row = m0 + wm + mt * 16 + quad * 4 + r;
        out[(size_t)row * HID + col] = acc[mt][nt][r];
      }
    }
}

// ---------------- launch ---------------------------------------------------------------
extern "C" void kernel_launch(void* const* d_in, const int* in_sizes, int n_in,
                              void* d_out, int out_size, void* d_ws, size_t ws_size,
                              hipStream_t stream) {
  const float* x  = (const float*)d_in[0];
  const float* Wq = (const float*)d_in[1];
  const float* Wk = (const float*)d_in[2];
  const float* Wv = (const float*)d_in[3];
  const float* Wo = (const float*)d_in[4];
  float* out = (float*)d_out;

  // d_out as scratch (all dead before out_gemm's writes):
  char* os = (char*)d_out;
  u16* Wqb = (u16*)(os);                     // 2MB   (dead after qkv)
  u16* Wkb = (u16*)(os + (2u << 20));        // 2MB
  u16* Wvb = (u16*)(os + (4u << 20));        // 2MB
  u16* xb  = (u16*)(os + (6u << 20));        // 8MB
  u16*   o1 = (u16*)(os);                    // 8MB partial O (z=1), post-qkv
  float* L0 = (float*)(os + (8u << 20));     // 256KB
  float* L1 = (float*)(os + (8u << 20) + (256u << 10));

  char* ws = (char*)d_ws;                    // 32MB
  u16* q    = (u16*)(ws);                    // 8MB; dead after flash
  u16* Wob  = (u16*)(ws);                    // 2MB over dead q
  u16* k    = (u16*)(ws + (8u << 20));       // 8MB
  u16* vT   = (u16*)(ws + (16u << 20));      // 8MB  [bh][d][s]
  u16* attn = (u16*)(ws + (24u << 20));      // 8MB; partial O (z=0), then combined

  cvt_pre<<<dim3(2048, 4), 256, 0, stream>>>(x, Wq, Wk, Wv, xb, Wqb, Wkb, Wvb);
  qkv_gemm<<<dim3(8, 32, 3), 256, 0, stream>>>(xb, Wqb, Wkb, Wvb, q, k, vT);
  flash<<<dim3(8, 32, 2), 256, 0, stream>>>(q, k, vT, attn, o1, L0, L1);
  cvt_wo<<<dim3(512), 256, 0, stream>>>(Wo, Wob);
  combine<<<dim3(2048), 256, 0, stream>>>(o1, L0, L1, attn);
  out_gemm<<<dim3(8, 64), 256, 0, stream>>>(attn, Wob, out);
}